// Round 5
// baseline (708.041 us; speedup 1.0000x reference)
//
#include <hip/hip_runtime.h>
#include <math.h>

// FICONN forward via split-bf16 MFMA (hi+lo, 3-product). R5 vs R4 (213us main, 163us build):
//  - Separate hi/lo LDS planes, ushort stride 136: B-frags are direct ds_read_b128 (zero repack).
//  - Split-pack via v_perm_b32 (RNE hi, trunc lo): ~2x fewer VALU in nofu/staging.
//  - 512 threads/block (8 waves), wave = (M-quarter, N-half): 4 waves/SIMD at 2 blocks/CU.
//  - Build: 4-wave cooperative sincos + 16-deep register prefetch ring for the scan.

#define NN 64
#define LL 5
#define NMZI 2016
#define C_HALF 0.7071067811865476f
#define GAMMA_ 0.05f
#define SENSRESP 0.0008f     // SENS*RESP

#define AH_SHORTS   114688   // 7 slots * 8Mt * 4Kt * 512
#define FLOAT_BYTE  458752
#define FROW 136             // ushorts per F row (272 B)

typedef short short8 __attribute__((ext_vector_type(8)));
typedef float f32x4  __attribute__((ext_vector_type(4)));

union U4S8 { uint4 u; short8 s; };

#define MFMA16(a, b, c) __builtin_amdgcn_mfma_f32_16x16x32_bf16((a), (b), (c), 0, 0, 0)

__device__ __forceinline__ unsigned short f2bf(float f) {
    unsigned u = __float_as_uint(f);
    unsigned r = u + 0x7fffu + ((u >> 16) & 1u);
    return (unsigned short)(r >> 16);
}
__device__ __forceinline__ float bf2f(unsigned short h) {
    return __uint_as_float(((unsigned)h) << 16);
}
// rounded-bits: top 16 bits are the RNE bf16 of v
__device__ __forceinline__ unsigned rnebits(float v) {
    unsigned u = __float_as_uint(v);
    return u + 0x7fffu + ((u >> 16) & 1u);
}
// (hi16(b) << 16) | hi16(a)  -- one v_perm_b32
__device__ __forceinline__ unsigned permhi16(unsigned a, unsigned b) {
    return __builtin_amdgcn_perm(a, b, 0x03020706);
}
// split 4 floats -> hi-plane uint2 (RNE bf16 pairs) + lo-plane uint2 (trunc bf16 pairs)
__device__ __forceinline__ void split4(const float* v, uint2& hi, uint2& lo) {
    unsigned r0 = rnebits(v[0]), r1 = rnebits(v[1]);
    unsigned r2 = rnebits(v[2]), r3 = rnebits(v[3]);
    hi.x = permhi16(r0, r1);
    hi.y = permhi16(r2, r3);
    float l0 = v[0] - __uint_as_float(r0 & 0xffff0000u);
    float l1 = v[1] - __uint_as_float(r1 & 0xffff0000u);
    float l2 = v[2] - __uint_as_float(r2 & 0xffff0000u);
    float l3 = v[3] - __uint_as_float(r3 & 0xffff0000u);
    lo.x = permhi16(__float_as_uint(l0), __float_as_uint(l1));
    lo.y = permhi16(__float_as_uint(l2), __float_as_uint(l3));
}
// frag-linear offset (in shorts) of element (m,k) of A-slot l
__device__ __forceinline__ int afrag_off(int l, int m, int k) {
    return ((((l * 8 + (m >> 4)) * 4 + (k >> 5)) << 9)
          + ((((k >> 3) & 3) * 16 + (m & 15)) << 3) + (k & 7));
}

// ---------------------------------------------------------------------------
// Kernel 1: build the 5 unitaries. 256 threads: all 4 waves compute sincos
// into LDS; wave 0 runs the fully-unrolled 2016-step scan with a 16-deep
// register prefetch ring (covers ds_read latency). Stores split-bf16 A-frags
// of Mat = [[Ur,-Ui],[Ui,Ur]] (output phases folded).
// ---------------------------------------------------------------------------
__global__ __launch_bounds__(256, 1) void build_unitaries(
    const float* __restrict__ mzi, const float* __restrict__ oph,
    unsigned short* __restrict__ AH)
{
    unsigned short* AL = AH + AH_SHORTS;
    const int l = blockIdx.x;
    const int tid = threadIdx.x;

    __shared__ float4 cs4[NMZI];
    __shared__ float2 ocs2[NN];

    for (int m = tid; m < NMZI; m += 256) {
        float th = mzi[l * 2 * NMZI + 2 * m];
        float ph = mzi[l * 2 * NMZI + 2 * m + 1];
        float sth, cth, sph, cph;
        sincosf(th, &sth, &cth);
        sincosf(ph, &sph, &cph);
        cs4[m] = make_float4(cph, sph, C_HALF * cth, C_HALF * sth);
    }
    if (tid < NN) {
        float sp, cp; sincosf(oph[l * NN + tid], &sp, &cp);
        ocs2[tid] = make_float2(cp, sp);
    }
    __syncthreads();
    if (tid >= 64) return;
    const int c = tid;

    float ur[NN], ui[NN];
    #pragma unroll
    for (int r = 0; r < NN; ++r) { ur[r] = (r == c) ? 1.f : 0.f; ui[r] = 0.f; }

    float4 qb[16];
    #pragma unroll
    for (int t = 0; t < 16; ++t) qb[t] = cs4[t];

    int m = 0;
    #pragma unroll
    for (int i = 0; i < NN - 1; ++i) {
        #pragma unroll
        for (int j = i + 1; j < NN; ++j) {
            float4 qq = qb[m & 15];
            if (m + 16 < NMZI) qb[m & 15] = cs4[m + 16];
            float tr = qq.x * ur[j] - qq.y * ui[j];
            float ti = qq.x * ui[j] + qq.y * ur[j];
            float ar = ur[i] + tr, ai = ui[i] + ti;
            float sr = ur[i] - tr, si = ui[i] - ti;
            ur[i] = C_HALF * ar;
            ui[i] = C_HALF * ai;
            ur[j] = qq.z * sr - qq.w * si;
            ui[j] = qq.z * si + qq.w * sr;
            ++m;
        }
    }
    // fold output phases
    #pragma unroll
    for (int r = 0; r < NN; ++r) {
        float2 oc = ocs2[r];
        float vr = oc.x * ur[r] - oc.y * ui[r];
        float vi = oc.x * ui[r] + oc.y * ur[r];
        ur[r] = vr; ui[r] = vi;
    }
    // thread c owns Mat columns k=c (Ur;Ui) and k=c+64 (-Ui;Ur)
    #pragma unroll
    for (int mm = 0; mm < 128; ++mm) {
        float v1 = (mm < 64) ? ur[mm] : ui[mm - 64];
        float v2 = (mm < 64) ? -ui[mm] : ur[mm - 64];
        int o1 = afrag_off(l, mm, c);
        int o2 = afrag_off(l, mm, c + 64);
        unsigned short h1 = f2bf(v1), h2 = f2bf(v2);
        AH[o1] = h1; AL[o1] = f2bf(v1 - bf2f(h1));
        AH[o2] = h2; AL[o2] = f2bf(v2 - bf2f(h2));
    }
}

// ---------------------------------------------------------------------------
// Kernel 2: W1 -> A-slot 5, W2 -> A-slot 6 (split bf16 frags), W3T, nofu consts.
// ---------------------------------------------------------------------------
__global__ void prep_weights(const float* __restrict__ W1,
                             const float* __restrict__ W2,
                             const float* __restrict__ W3,
                             const float* __restrict__ beta_param,
                             const float* __restrict__ det0,
                             unsigned short* __restrict__ AH)
{
    unsigned short* AL = AH + AH_SHORTS;
    float* fbase = (float*)((char*)AH + FLOAT_BYTE);
    float* nofuF = fbase;               // 1024 floats (256 x float4)
    float* W3T   = fbase + 1024;        // 768 floats

    int idx = blockIdx.x * 256 + threadIdx.x;
    if (idx < 8192) {                        // W1 (128x64)
        int mm = idx >> 6, k = idx & 63;
        float v = W1[idx];
        unsigned short h = f2bf(v);
        int o = afrag_off(5, mm, k);
        AH[o] = h; AL[o] = f2bf(v - bf2f(h));
    } else if (idx < 16384) {                // W2 (64x128)
        int t = idx - 8192;
        int mm = t >> 7, k = t & 127;
        float v = W2[t];
        unsigned short h = f2bf(v);
        int o = afrag_off(6, mm, k);
        AH[o] = h; AL[o] = f2bf(v - bf2f(h));
    } else if (idx < 17152) {                // W3 (12x64) -> W3T[j][r]
        int t = idx - 16384;
        int r = t >> 6, j = t & 63;
        W3T[j * 12 + r] = W3[t];
    } else if (idx < 17408) {                // nofu consts, t = l*64+row
        int t = idx - 17152;
        float bp = beta_param[t];
        float beta = 1.f / (1.f + expf(-bp));
        float* p = nofuF + t * 4;
        p[0] = SENSRESP * beta;
        p[1] = sqrtf(fmaxf(1.f - beta, 0.f)) * GAMMA_;
        p[2] = det0[t];
        p[3] = 0.f;
    }
}

// ---------------------------------------------------------------------------
// Matmul block helper: C[Mt tile(s)] += A_slot x F. PAIR: also Mt0+4 into acc1.
// ---------------------------------------------------------------------------
template<int K4, bool PAIR>
__device__ __forceinline__ void mm_block(
    const unsigned short* __restrict__ AH, const unsigned short* __restrict__ AL,
    const unsigned short* Fh, const unsigned short* Fl,
    int slot, int mt0, int lane, int q, const int* brow,
    f32x4* acc0, f32x4* acc1)
{
    #pragma unroll
    for (int Kt = 0; Kt < K4; ++Kt) {
        int off0 = (((slot * 8 + mt0) * 4 + Kt) << 9);
        U4S8 ah0, al0, ah1, al1;
        ah0.u = ((const uint4*)(AH + off0))[lane];
        al0.u = ((const uint4*)(AL + off0))[lane];
        if (PAIR) {
            ah1.u = ((const uint4*)(AH + off0 + 8192))[lane];   // Mt0+4
            al1.u = ((const uint4*)(AL + off0 + 8192))[lane];
        }
        #pragma unroll
        for (int t = 0; t < 4; ++t) {
            short8 bh = *(const short8*)&Fh[brow[t] + 32 * Kt + 8 * q];
            short8 bl = *(const short8*)&Fl[brow[t] + 32 * Kt + 8 * q];
            acc0[t] = MFMA16(ah0.s, bh, acc0[t]);
            acc0[t] = MFMA16(ah0.s, bl, acc0[t]);
            acc0[t] = MFMA16(al0.s, bh, acc0[t]);
            if (PAIR) {
                acc1[t] = MFMA16(ah1.s, bh, acc1[t]);
                acc1[t] = MFMA16(ah1.s, bl, acc1[t]);
                acc1[t] = MFMA16(al1.s, bh, acc1[t]);
            }
        }
    }
}

// ---------------------------------------------------------------------------
// Kernel 3: main. 128 samples/block, 512 threads (8 waves).
// wave w: mp=w&3 (M quarter), nh=w>>2 (N half). Unitary layers / W1: wave owns
// Mt in {mp, mp+4} (pairing rows m and m+64 for nofu). W2: Mt=mp.
// ---------------------------------------------------------------------------
__global__ __launch_bounds__(512, 4) void ficonn_main(
    const float* __restrict__ x,
    const float* __restrict__ b1,
    const float* __restrict__ b2,
    const float* __restrict__ b3,
    const unsigned short* __restrict__ AH,
    const float4* __restrict__ nofuC,
    const float* __restrict__ W3T,
    float* __restrict__ out)
{
    const unsigned short* AL = AH + AH_SHORTS;
    extern __shared__ unsigned short Fdyn[];
    unsigned short* Fh = Fdyn;                  // 128 x FROW
    unsigned short* Fl = Fdyn + 128 * FROW;

    const int tid  = threadIdx.x;
    const int lane = tid & 63;
    const int w    = __builtin_amdgcn_readfirstlane(tid >> 6);   // 0..7
    const int mp   = w & 3, nh = w >> 2;
    const int n16  = lane & 15, q = lane >> 4;
    const int base = blockIdx.x * 128;

    // ---- stage x (split bf16, hi/lo planes); input real -> k<64 only ----
    {
        const float4* x4 = (const float4*)(x + (size_t)base * 64);
        #pragma unroll
        for (int it = 0; it < 4; ++it) {
            int idx = tid + it * 512;           // 2048 float4
            int j4 = idx & 15, ss = idx >> 4;
            float4 v4 = x4[idx];
            float vv[4] = {v4.x, v4.y, v4.z, v4.w};
            uint2 hi, lo; split4(vv, hi, lo);
            *(uint2*)&Fh[ss * FROW + 4 * j4] = hi;
            *(uint2*)&Fl[ss * FROW + 4 * j4] = lo;
        }
    }
    __syncthreads();

    int brow[4];
    #pragma unroll
    for (int t = 0; t < 4; ++t) brow[t] = (64 * nh + 16 * t + n16) * FROW;
    const int kw = 16 * mp + 4 * q;             // this wave's output k-base

    // ================= 5 unitary layers =================
    #pragma unroll 1
    for (int l = 0; l < 5; ++l) {
        f32x4 acc0[4], acc1[4];
        #pragma unroll
        for (int t = 0; t < 4; ++t)
            #pragma unroll
            for (int r = 0; r < 4; ++r) { acc0[t][r] = 0.f; acc1[t][r] = 0.f; }

        if (l == 0) mm_block<2, true>(AH, AL, Fh, Fl, 0, mp, lane, q, brow, acc0, acc1);
        else        mm_block<4, true>(AH, AL, Fh, Fl, l, mp, lane, q, brow, acc0, acc1);
        __syncthreads();   // all F reads done

        if (l < 4) {
            float4 nc[4];
            #pragma unroll
            for (int r = 0; r < 4; ++r) nc[r] = nofuC[l * 64 + kw + r];
            #pragma unroll
            for (int t = 0; t < 4; ++t) {
                float wr[4], wi[4];
                #pragma unroll
                for (int r = 0; r < 4; ++r) {
                    float yr = acc0[t][r], yi = acc1[t][r];
                    float4 c = nc[r];
                    float p   = fmaf(yr, yr, yi * yi);
                    float det = fmaf(c.x, p, c.z);
                    float sc  = c.y * __builtin_amdgcn_rcpf(fmaf(det, det, GAMMA_ * GAMMA_));
                    float tr = sc * GAMMA_, ti = sc * det;
                    wr[r] = fmaf(tr, yr,  ti * yi);
                    wi[r] = fmaf(tr, yi, -ti * yr);
                }
                uint2 hi, lo;
                split4(wr, hi, lo);
                *(uint2*)&Fh[brow[t] + kw] = hi;
                *(uint2*)&Fl[brow[t] + kw] = lo;
                split4(wi, hi, lo);
                *(uint2*)&Fh[brow[t] + kw + 64] = hi;
                *(uint2*)&Fl[brow[t] + kw + 64] = lo;
            }
        } else {
            #pragma unroll
            for (int t = 0; t < 4; ++t) {
                float pw[4];
                #pragma unroll
                for (int r = 0; r < 4; ++r)
                    pw[r] = fmaf(acc0[t][r], acc0[t][r], acc1[t][r] * acc1[t][r]);
                uint2 hi, lo;
                split4(pw, hi, lo);
                *(uint2*)&Fh[brow[t] + kw] = hi;
                *(uint2*)&Fl[brow[t] + kw] = lo;
            }
        }
        __syncthreads();
    }

    // ================= W1: M=128, K=64 (slot 5), Mt in {mp, mp+4} =================
    {
        f32x4 acc0[4], acc1[4];
        #pragma unroll
        for (int t = 0; t < 4; ++t)
            #pragma unroll
            for (int r = 0; r < 4; ++r) { acc0[t][r] = 0.f; acc1[t][r] = 0.f; }

        mm_block<2, true>(AH, AL, Fh, Fl, 5, mp, lane, q, brow, acc0, acc1);
        __syncthreads();

        float4 bb0 = *(const float4*)&b1[kw];
        float4 bb1 = *(const float4*)&b1[kw + 64];
        #pragma unroll
        for (int t = 0; t < 4; ++t) {
            float h0[4], h1v[4];
            #pragma unroll
            for (int r = 0; r < 4; ++r) {
                h0[r]  = fmaxf(acc0[t][r] + ((const float*)&bb0)[r], 0.f);
                h1v[r] = fmaxf(acc1[t][r] + ((const float*)&bb1)[r], 0.f);
            }
            uint2 hi, lo;
            split4(h0, hi, lo);
            *(uint2*)&Fh[brow[t] + kw] = hi;
            *(uint2*)&Fl[brow[t] + kw] = lo;
            split4(h1v, hi, lo);
            *(uint2*)&Fh[brow[t] + kw + 64] = hi;
            *(uint2*)&Fl[brow[t] + kw + 64] = lo;
        }
        __syncthreads();
    }

    // ================= W2: M=64, K=128 (slot 6), Mt=mp =================
    {
        f32x4 acc0[4], acc1[4];   // acc1 unused
        #pragma unroll
        for (int t = 0; t < 4; ++t)
            #pragma unroll
            for (int r = 0; r < 4; ++r) acc0[t][r] = 0.f;

        mm_block<4, false>(AH, AL, Fh, Fl, 6, mp, lane, q, brow, acc0, acc1);
        __syncthreads();

        float4 bb = *(const float4*)&b2[kw];
        #pragma unroll
        for (int t = 0; t < 4; ++t) {
            float h[4];
            #pragma unroll
            for (int r = 0; r < 4; ++r)
                h[r] = fmaxf(acc0[t][r] + ((const float*)&bb)[r], 0.f);
            uint2 hi, lo;
            split4(h, hi, lo);
            *(uint2*)&Fh[brow[t] + kw] = hi;
            *(uint2*)&Fl[brow[t] + kw] = lo;
        }
        __syncthreads();
    }

    // ================= W3: fp32 VALU, thread = sample (tid<128) =================
    if (tid < 128) {
        int n = tid;
        float o[12];
        #pragma unroll
        for (int r = 0; r < 12; ++r) o[r] = b3[r];
        const unsigned short* rh = &Fh[n * FROW];
        const unsigned short* rl = &Fl[n * FROW];
        #pragma unroll
        for (int kc = 0; kc < 8; ++kc) {
            uint4 ph = *(const uint4*)&rh[8 * kc];
            uint4 pl = *(const uint4*)&rl[8 * kc];
            unsigned hu[4] = {ph.x, ph.y, ph.z, ph.w};
            unsigned lu[4] = {pl.x, pl.y, pl.z, pl.w};
            #pragma unroll
            for (int e = 0; e < 4; ++e) {
                int k = 8 * kc + 2 * e;
                float ha = __uint_as_float(hu[e] << 16) + __uint_as_float(lu[e] << 16);
                float hb = __uint_as_float(hu[e] & 0xffff0000u)
                         + __uint_as_float(lu[e] & 0xffff0000u);
                const float* wa = W3T + k * 12;
                const float* wb = W3T + (k + 1) * 12;
                #pragma unroll
                for (int r = 0; r < 12; ++r)
                    o[r] = fmaf(wa[r], ha, fmaf(wb[r], hb, o[r]));
            }
        }
        float4* op = (float4*)(out + (size_t)(base + n) * 12);
        op[0] = make_float4(o[0], o[1], o[2],  o[3]);
        op[1] = make_float4(o[4], o[5], o[6],  o[7]);
        op[2] = make_float4(o[8], o[9], o[10], o[11]);
    }
}

extern "C" void kernel_launch(void* const* d_in, const int* in_sizes, int n_in,
                              void* d_out, int out_size, void* d_ws, size_t ws_size,
                              hipStream_t stream)
{
    const float* x    = (const float*)d_in[0];
    const float* mzi  = (const float*)d_in[1];
    const float* oph  = (const float*)d_in[2];
    const float* beta = (const float*)d_in[3];
    const float* det0 = (const float*)d_in[4];
    const float* W1   = (const float*)d_in[5];
    const float* b1   = (const float*)d_in[6];
    const float* W2   = (const float*)d_in[7];
    const float* b2   = (const float*)d_in[8];
    const float* W3   = (const float*)d_in[9];
    const float* b3   = (const float*)d_in[10];
    float* out = (float*)d_out;

    unsigned short* AH = (unsigned short*)d_ws;
    float* fbase = (float*)((char*)d_ws + FLOAT_BYTE);
    const float4* nofuC = (const float4*)fbase;
    const float* W3T = fbase + 1024;

    const int B = in_sizes[0] / NN;       // 262144
    const int blocks = B / 128;           // 2048
    const size_t lds_bytes = 2u * 128u * FROW * sizeof(unsigned short);  // 69632

    hipLaunchKernelGGL(build_unitaries, dim3(LL), dim3(256), 0, stream, mzi, oph, AH);
    hipLaunchKernelGGL(prep_weights, dim3(68), dim3(256), 0, stream,
                       W1, W2, W3, beta, det0, AH);
    hipLaunchKernelGGL(ficonn_main, dim3(blocks), dim3(512), lds_bytes, stream,
                       x, b1, b2, b3, AH, nofuC, W3T, out);
}

// Round 6
// 319.581 us; speedup vs baseline: 2.2155x; 2.2155x over previous
//
#include <hip/hip_runtime.h>
#include <math.h>

// FICONN forward, split-bf16 MFMA (hi+lo, 3-product) + segment-parallel unitary build.
// R6 vs R5: build_unitaries spilled (450us, VGPR=112, scratch chain ~530cyc/step).
//  - Build split: U = P3*P2*P1*P0. build_seg = 20 blocks x 64 thr, R4-proven scan shape
//    (scalar cs loads, LB(64), register state) over ~500-step i-chunks -> fp32 P to ws.
//    build_combine = 5 blocks x 256 thr: LDS-staged 3 matmul passes + psi fold + frag store.
//  - Main: R5 structure (hi/lo LDS planes, direct ds_read_b128 B-frags, 8 waves) +
//    W3 tail spread over all 512 threads.

#define NN 64
#define LL 5
#define NMZI 2016
#define C_HALF 0.7071067811865476f
#define GAMMA_ 0.05f
#define SENSRESP 0.0008f     // SENS*RESP

#define AH_SHORTS   114688   // 7 slots * 8Mt * 4Kt * 512 shorts
#define FLOAT_BYTE  458752   // nofuC (1024 f) + W3T (768 f)
#define PSEG_BYTE   466944   // 5l x 4s x 64c x 64r float2 = 655360 B
#define FROW 136             // ushorts per F row (272 B)

typedef short short8 __attribute__((ext_vector_type(8)));
typedef float f32x4  __attribute__((ext_vector_type(4)));

union U4S8 { uint4 u; short8 s; };

#define MFMA16(a, b, c) __builtin_amdgcn_mfma_f32_16x16x32_bf16((a), (b), (c), 0, 0, 0)

__device__ __forceinline__ unsigned short f2bf(float f) {
    unsigned u = __float_as_uint(f);
    unsigned r = u + 0x7fffu + ((u >> 16) & 1u);
    return (unsigned short)(r >> 16);
}
__device__ __forceinline__ float bf2f(unsigned short h) {
    return __uint_as_float(((unsigned)h) << 16);
}
__device__ __forceinline__ unsigned rnebits(float v) {
    unsigned u = __float_as_uint(v);
    return u + 0x7fffu + ((u >> 16) & 1u);
}
__device__ __forceinline__ unsigned permhi16(unsigned a, unsigned b) {
    return __builtin_amdgcn_perm(a, b, 0x03020706);
}
__device__ __forceinline__ void split4(const float* v, uint2& hi, uint2& lo) {
    unsigned r0 = rnebits(v[0]), r1 = rnebits(v[1]);
    unsigned r2 = rnebits(v[2]), r3 = rnebits(v[3]);
    hi.x = permhi16(r0, r1);
    hi.y = permhi16(r2, r3);
    float l0 = v[0] - __uint_as_float(r0 & 0xffff0000u);
    float l1 = v[1] - __uint_as_float(r1 & 0xffff0000u);
    float l2 = v[2] - __uint_as_float(r2 & 0xffff0000u);
    float l3 = v[3] - __uint_as_float(r3 & 0xffff0000u);
    lo.x = permhi16(__float_as_uint(l0), __float_as_uint(l1));
    lo.y = permhi16(__float_as_uint(l2), __float_as_uint(l3));
}
// frag-linear offset (in shorts) of element (m,k) of A-slot l
__device__ __forceinline__ int afrag_off(int l, int m, int k) {
    return ((((l * 8 + (m >> 4)) * 4 + (k >> 5)) << 9)
          + ((((k >> 3) & 3) * 16 + (m & 15)) << 3) + (k & 7));
}

// ---------------------------------------------------------------------------
// Kernel 1: build_seg. 20 blocks (layer l, segment s) x 64 threads.
// Thread = column c of partial product P_s (register state, unrolled scan --
// exact R4-proven structure: scalar cs loads, LB(64)).
// Segments by i-range: [0,9)=531, [9,19)=495, [19,31)=462, [31,63)=528 steps.
// ---------------------------------------------------------------------------
template<int I0, int I1>
__device__ __forceinline__ void run_scan(const float cs[][4], float* ur, float* ui)
{
    int m = 0;
    #pragma unroll
    for (int i = I0; i < I1; ++i) {
        #pragma unroll
        for (int j = i + 1; j < NN; ++j) {
            float cph = cs[m][0], sph = cs[m][1];
            float cct = cs[m][2], cst = cs[m][3];
            float tr = cph * ur[j] - sph * ui[j];
            float ti = cph * ui[j] + sph * ur[j];
            float ar = ur[i] + tr, ai = ui[i] + ti;
            float sr = ur[i] - tr, si = ui[i] - ti;
            ur[i] = C_HALF * ar;
            ui[i] = C_HALF * ai;
            ur[j] = cct * sr - cst * si;
            ui[j] = cct * si + cst * sr;
            ++m;
        }
    }
}

__global__ __launch_bounds__(64) void build_seg(
    const float* __restrict__ mzi, float2* __restrict__ Pg)
{
    const int b = blockIdx.x;
    const int l = b >> 2, s = b & 3;
    const int c = threadIdx.x;

    __shared__ float cs[531][4];
    const int M0s[5] = {0, 531, 1026, 1488, 2016};
    const int m0 = M0s[s], cnt = M0s[s + 1] - m0;

    for (int t = c; t < cnt; t += 64) {
        int m = m0 + t;
        float th = mzi[l * 2 * NMZI + 2 * m];
        float ph = mzi[l * 2 * NMZI + 2 * m + 1];
        float sth, cth, sph, cph;
        sincosf(th, &sth, &cth);
        sincosf(ph, &sph, &cph);
        cs[t][0] = cph; cs[t][1] = sph;
        cs[t][2] = C_HALF * cth; cs[t][3] = C_HALF * sth;
    }
    __syncthreads();

    float ur[NN], ui[NN];
    #pragma unroll
    for (int r = 0; r < NN; ++r) { ur[r] = (r == c) ? 1.f : 0.f; ui[r] = 0.f; }

    switch (s) {
        case 0: run_scan<0,  9>(cs, ur, ui); break;
        case 1: run_scan<9, 19>(cs, ur, ui); break;
        case 2: run_scan<19,31>(cs, ur, ui); break;
        default:run_scan<31,63>(cs, ur, ui); break;
    }

    // store column-major: Pg[(l*4+s)*4096 + c*64 + r]
    float2* P = Pg + ((size_t)(l * 4 + s) << 12) + (c << 6);
    #pragma unroll
    for (int r = 0; r < NN; ++r) P[r] = make_float2(ur[r], ui[r]);
}

// ---------------------------------------------------------------------------
// Kernel 2: build_combine. 5 blocks x 256 threads. Stage P0..P3 into padded
// LDS, compute T1=P1*P0, T2=P3*P2, U=T2*T1 (thread = (row-quarter rq, col c),
// 16 complex accs), fold output phases, store split-bf16 A-frags.
// ---------------------------------------------------------------------------
__device__ __forceinline__ void cpass(const float2* A, const float2* Bm,
                                      int rq, int c, float2* y)
{
    #pragma unroll
    for (int r = 0; r < 16; ++r) y[r] = make_float2(0.f, 0.f);
    #pragma unroll 2
    for (int k = 0; k < 64; ++k) {
        float2 x = Bm[c * 65 + k];                  // own column, 2-way bank (free)
        #pragma unroll
        for (int r = 0; r < 16; ++r) {
            float2 a = A[k * 65 + 16 * rq + r];     // wave-uniform -> broadcast
            y[r].x = fmaf(a.x, x.x, fmaf(-a.y, x.y, y[r].x));
            y[r].y = fmaf(a.x, x.y, fmaf( a.y, x.x, y[r].y));
        }
    }
}

__device__ __forceinline__ void store_split(unsigned short* AH, unsigned short* AL,
                                            int l, int m, int k, float v)
{
    int o = afrag_off(l, m, k);
    unsigned short h = f2bf(v);
    AH[o] = h;
    AL[o] = f2bf(v - bf2f(h));
}

__global__ __launch_bounds__(256) void build_combine(
    const float2* __restrict__ Pg, const float* __restrict__ oph,
    unsigned short* __restrict__ AH)
{
    unsigned short* AL = AH + AH_SHORTS;
    extern __shared__ float cl[];
    float2* B0 = (float2*)cl;              // 64 x 65 f2 each
    float2* B1 = B0 + 4160;
    float2* B2 = B1 + 4160;
    float2* B3 = B2 + 4160;
    float2* ocs = B3 + 4160;               // 64 f2

    const int l = blockIdx.x;
    const int tid = threadIdx.x;
    const int rq = tid >> 6, c = tid & 63;

    const float2* Pgl = Pg + ((size_t)l << 14);
    #pragma unroll
    for (int sb = 0; sb < 4; ++sb) {
        float2* Bb = B0 + sb * 4160;
        #pragma unroll
        for (int i = 0; i < 16; ++i) {
            int idx = tid + i * 256;
            Bb[(idx >> 6) * 65 + (idx & 63)] = Pgl[(sb << 12) + idx];
        }
    }
    if (tid < NN) {
        float sp, cp; sincosf(oph[l * NN + tid], &sp, &cp);
        ocs[tid] = make_float2(cp, sp);
    }
    __syncthreads();

    float2 t1[16], t2[16];
    cpass(B1, B0, rq, c, t1);   // T1 = P1*P0
    cpass(B3, B2, rq, c, t2);   // T2 = P3*P2
    __syncthreads();
    #pragma unroll
    for (int r = 0; r < 16; ++r) {
        B0[c * 65 + 16 * rq + r] = t1[r];
        B2[c * 65 + 16 * rq + r] = t2[r];
    }
    __syncthreads();

    float2 u[16];
    cpass(B2, B0, rq, c, u);    // U = T2*T1

    #pragma unroll
    for (int r = 0; r < 16; ++r) {
        int mr = 16 * rq + r;
        float2 oc = ocs[mr];
        float vr = oc.x * u[r].x - oc.y * u[r].y;   // e^{i psi_mr} * U[mr][c]
        float vi = oc.x * u[r].y + oc.y * u[r].x;
        // Mat = [[Ur,-Ui],[Ui,Ur]]
        store_split(AH, AL, l, mr,      c,      vr);
        store_split(AH, AL, l, mr,      c + 64, -vi);
        store_split(AH, AL, l, mr + 64, c,      vi);
        store_split(AH, AL, l, mr + 64, c + 64, vr);
    }
}

// ---------------------------------------------------------------------------
// Kernel 3: W1 -> A-slot 5, W2 -> A-slot 6 (split bf16 frags), W3T, nofu consts.
// ---------------------------------------------------------------------------
__global__ void prep_weights(const float* __restrict__ W1,
                             const float* __restrict__ W2,
                             const float* __restrict__ W3,
                             const float* __restrict__ beta_param,
                             const float* __restrict__ det0,
                             unsigned short* __restrict__ AH)
{
    unsigned short* AL = AH + AH_SHORTS;
    float* fbase = (float*)((char*)AH + FLOAT_BYTE);
    float* nofuF = fbase;               // 1024 floats (256 x float4)
    float* W3T   = fbase + 1024;        // 768 floats

    int idx = blockIdx.x * 256 + threadIdx.x;
    if (idx < 8192) {                        // W1 (128x64)
        int mm = idx >> 6, k = idx & 63;
        float v = W1[idx];
        unsigned short h = f2bf(v);
        int o = afrag_off(5, mm, k);
        AH[o] = h; AL[o] = f2bf(v - bf2f(h));
    } else if (idx < 16384) {                // W2 (64x128)
        int t = idx - 8192;
        int mm = t >> 7, k = t & 127;
        float v = W2[t];
        unsigned short h = f2bf(v);
        int o = afrag_off(6, mm, k);
        AH[o] = h; AL[o] = f2bf(v - bf2f(h));
    } else if (idx < 17152) {                // W3 (12x64) -> W3T[j][r]
        int t = idx - 16384;
        int r = t >> 6, j = t & 63;
        W3T[j * 12 + r] = W3[t];
    } else if (idx < 17408) {                // nofu consts, t = l*64+row
        int t = idx - 17152;
        float bp = beta_param[t];
        float beta = 1.f / (1.f + expf(-bp));
        float* p = nofuF + t * 4;
        p[0] = SENSRESP * beta;
        p[1] = sqrtf(fmaxf(1.f - beta, 0.f)) * GAMMA_;
        p[2] = det0[t];
        p[3] = 0.f;
    }
}

// ---------------------------------------------------------------------------
// Matmul block helper: C[Mt tile(s)] += A_slot x F. PAIR: also Mt0+4 into acc1.
// ---------------------------------------------------------------------------
template<int K4, bool PAIR>
__device__ __forceinline__ void mm_block(
    const unsigned short* __restrict__ AH, const unsigned short* __restrict__ AL,
    const unsigned short* Fh, const unsigned short* Fl,
    int slot, int mt0, int lane, int q, const int* brow,
    f32x4* acc0, f32x4* acc1)
{
    #pragma unroll
    for (int Kt = 0; Kt < K4; ++Kt) {
        int off0 = (((slot * 8 + mt0) * 4 + Kt) << 9);
        U4S8 ah0, al0, ah1, al1;
        ah0.u = ((const uint4*)(AH + off0))[lane];
        al0.u = ((const uint4*)(AL + off0))[lane];
        if (PAIR) {
            ah1.u = ((const uint4*)(AH + off0 + 8192))[lane];   // Mt0+4
            al1.u = ((const uint4*)(AL + off0 + 8192))[lane];
        }
        #pragma unroll
        for (int t = 0; t < 4; ++t) {
            short8 bh = *(const short8*)&Fh[brow[t] + 32 * Kt + 8 * q];
            short8 bl = *(const short8*)&Fl[brow[t] + 32 * Kt + 8 * q];
            acc0[t] = MFMA16(ah0.s, bh, acc0[t]);
            acc0[t] = MFMA16(ah0.s, bl, acc0[t]);
            acc0[t] = MFMA16(al0.s, bh, acc0[t]);
            if (PAIR) {
                acc1[t] = MFMA16(ah1.s, bh, acc1[t]);
                acc1[t] = MFMA16(ah1.s, bl, acc1[t]);
                acc1[t] = MFMA16(al1.s, bh, acc1[t]);
            }
        }
    }
}

// ---------------------------------------------------------------------------
// Kernel 4: main. 128 samples/block, 512 threads (8 waves).
// wave w: mp=w&3 (M quarter), nh=w>>2 (N half). Unitary layers / W1: wave owns
// Mt in {mp, mp+4} (pairing rows m and m+64 for nofu). W2: Mt=mp.
// ---------------------------------------------------------------------------
__global__ __launch_bounds__(512, 4) void ficonn_main(
    const float* __restrict__ x,
    const float* __restrict__ b1,
    const float* __restrict__ b2,
    const float* __restrict__ b3,
    const unsigned short* __restrict__ AH,
    const float4* __restrict__ nofuC,
    const float* __restrict__ W3T,
    float* __restrict__ out)
{
    const unsigned short* AL = AH + AH_SHORTS;
    extern __shared__ unsigned short Fdyn[];
    unsigned short* Fh = Fdyn;                  // 128 x FROW
    unsigned short* Fl = Fdyn + 128 * FROW;

    const int tid  = threadIdx.x;
    const int lane = tid & 63;
    const int w    = __builtin_amdgcn_readfirstlane(tid >> 6);   // 0..7
    const int mp   = w & 3, nh = w >> 2;
    const int n16  = lane & 15, q = lane >> 4;
    const int base = blockIdx.x * 128;

    // ---- stage x (split bf16, hi/lo planes); input real -> k<64 only ----
    {
        const float4* x4 = (const float4*)(x + (size_t)base * 64);
        #pragma unroll
        for (int it = 0; it < 4; ++it) {
            int idx = tid + it * 512;           // 2048 float4
            int j4 = idx & 15, ss = idx >> 4;
            float4 v4 = x4[idx];
            float vv[4] = {v4.x, v4.y, v4.z, v4.w};
            uint2 hi, lo; split4(vv, hi, lo);
            *(uint2*)&Fh[ss * FROW + 4 * j4] = hi;
            *(uint2*)&Fl[ss * FROW + 4 * j4] = lo;
        }
    }
    __syncthreads();

    int brow[4];
    #pragma unroll
    for (int t = 0; t < 4; ++t) brow[t] = (64 * nh + 16 * t + n16) * FROW;
    const int kw = 16 * mp + 4 * q;             // this wave's output k-base

    // ================= 5 unitary layers =================
    #pragma unroll 1
    for (int l = 0; l < 5; ++l) {
        f32x4 acc0[4], acc1[4];
        #pragma unroll
        for (int t = 0; t < 4; ++t)
            #pragma unroll
            for (int r = 0; r < 4; ++r) { acc0[t][r] = 0.f; acc1[t][r] = 0.f; }

        if (l == 0) mm_block<2, true>(AH, AL, Fh, Fl, 0, mp, lane, q, brow, acc0, acc1);
        else        mm_block<4, true>(AH, AL, Fh, Fl, l, mp, lane, q, brow, acc0, acc1);
        __syncthreads();   // all F reads done

        if (l < 4) {
            float4 nc[4];
            #pragma unroll
            for (int r = 0; r < 4; ++r) nc[r] = nofuC[l * 64 + kw + r];
            #pragma unroll
            for (int t = 0; t < 4; ++t) {
                float wr[4], wi[4];
                #pragma unroll
                for (int r = 0; r < 4; ++r) {
                    float yr = acc0[t][r], yi = acc1[t][r];
                    float4 c = nc[r];
                    float p   = fmaf(yr, yr, yi * yi);
                    float det = fmaf(c.x, p, c.z);
                    float sc  = c.y * __builtin_amdgcn_rcpf(fmaf(det, det, GAMMA_ * GAMMA_));
                    float tr = sc * GAMMA_, ti = sc * det;
                    wr[r] = fmaf(tr, yr,  ti * yi);
                    wi[r] = fmaf(tr, yi, -ti * yr);
                }
                uint2 hi, lo;
                split4(wr, hi, lo);
                *(uint2*)&Fh[brow[t] + kw] = hi;
                *(uint2*)&Fl[brow[t] + kw] = lo;
                split4(wi, hi, lo);
                *(uint2*)&Fh[brow[t] + kw + 64] = hi;
                *(uint2*)&Fl[brow[t] + kw + 64] = lo;
            }
        } else {
            #pragma unroll
            for (int t = 0; t < 4; ++t) {
                float pw[4];
                #pragma unroll
                for (int r = 0; r < 4; ++r)
                    pw[r] = fmaf(acc0[t][r], acc0[t][r], acc1[t][r] * acc1[t][r]);
                uint2 hi, lo;
                split4(pw, hi, lo);
                *(uint2*)&Fh[brow[t] + kw] = hi;
                *(uint2*)&Fl[brow[t] + kw] = lo;
            }
        }
        __syncthreads();
    }

    // ================= W1: M=128, K=64 (slot 5), Mt in {mp, mp+4} =================
    {
        f32x4 acc0[4], acc1[4];
        #pragma unroll
        for (int t = 0; t < 4; ++t)
            #pragma unroll
            for (int r = 0; r < 4; ++r) { acc0[t][r] = 0.f; acc1[t][r] = 0.f; }

        mm_block<2, true>(AH, AL, Fh, Fl, 5, mp, lane, q, brow, acc0, acc1);
        __syncthreads();

        float4 bb0 = *(const float4*)&b1[kw];
        float4 bb1 = *(const float4*)&b1[kw + 64];
        #pragma unroll
        for (int t = 0; t < 4; ++t) {
            float h0[4], h1v[4];
            #pragma unroll
            for (int r = 0; r < 4; ++r) {
                h0[r]  = fmaxf(acc0[t][r] + ((const float*)&bb0)[r], 0.f);
                h1v[r] = fmaxf(acc1[t][r] + ((const float*)&bb1)[r], 0.f);
            }
            uint2 hi, lo;
            split4(h0, hi, lo);
            *(uint2*)&Fh[brow[t] + kw] = hi;
            *(uint2*)&Fl[brow[t] + kw] = lo;
            split4(h1v, hi, lo);
            *(uint2*)&Fh[brow[t] + kw + 64] = hi;
            *(uint2*)&Fl[brow[t] + kw + 64] = lo;
        }
        __syncthreads();
    }

    // ================= W2: M=64, K=128 (slot 6), Mt=mp =================
    {
        f32x4 acc0[4], acc1[4];   // acc1 unused
        #pragma unroll
        for (int t = 0; t < 4; ++t)
            #pragma unroll
            for (int r = 0; r < 4; ++r) acc0[t][r] = 0.f;

        mm_block<4, false>(AH, AL, Fh, Fl, 6, mp, lane, q, brow, acc0, acc1);
        __syncthreads();

        float4 bb = *(const float4*)&b2[kw];
        #pragma unroll
        for (int t = 0; t < 4; ++t) {
            float h[4];
            #pragma unroll
            for (int r = 0; r < 4; ++r)
                h[r] = fmaxf(acc0[t][r] + ((const float*)&bb)[r], 0.f);
            uint2 hi, lo;
            split4(h, hi, lo);
            *(uint2*)&Fh[brow[t] + kw] = hi;
            *(uint2*)&Fl[brow[t] + kw] = lo;
        }
        __syncthreads();
    }

    // ================= W3: fp32 VALU, all 512 threads: (sample, out-triple) ===
    {
        const int n  = tid & 127;
        const int rg = __builtin_amdgcn_readfirstlane(tid >> 7);   // 0..3
        float o0 = b3[3 * rg], o1 = b3[3 * rg + 1], o2 = b3[3 * rg + 2];
        const unsigned short* rh = &Fh[n * FROW];
        const unsigned short* rl = &Fl[n * FROW];
        #pragma unroll
        for (int kc = 0; kc < 8; ++kc) {
            uint4 ph = *(const uint4*)&rh[8 * kc];
            uint4 pl = *(const uint4*)&rl[8 * kc];
            unsigned hu[4] = {ph.x, ph.y, ph.z, ph.w};
            unsigned lu[4] = {pl.x, pl.y, pl.z, pl.w};
            #pragma unroll
            for (int e = 0; e < 4; ++e) {
                int k = 8 * kc + 2 * e;
                float ha = __uint_as_float(hu[e] << 16)
                         + __uint_as_float(lu[e] << 16);
                float hb = __uint_as_float(hu[e] & 0xffff0000u)
                         + __uint_as_float(lu[e] & 0xffff0000u);
                const float* wa = W3T + k * 12 + 3 * rg;
                const float* wb = wa + 12;
                o0 = fmaf(wa[0], ha, fmaf(wb[0], hb, o0));
                o1 = fmaf(wa[1], ha, fmaf(wb[1], hb, o1));
                o2 = fmaf(wa[2], ha, fmaf(wb[2], hb, o2));
            }
        }
        float* op = out + (size_t)(base + n) * 12 + 3 * rg;
        op[0] = o0; op[1] = o1; op[2] = o2;
    }
}

extern "C" void kernel_launch(void* const* d_in, const int* in_sizes, int n_in,
                              void* d_out, int out_size, void* d_ws, size_t ws_size,
                              hipStream_t stream)
{
    const float* x    = (const float*)d_in[0];
    const float* mzi  = (const float*)d_in[1];
    const float* oph  = (const float*)d_in[2];
    const float* beta = (const float*)d_in[3];
    const float* det0 = (const float*)d_in[4];
    const float* W1   = (const float*)d_in[5];
    const float* b1   = (const float*)d_in[6];
    const float* W2   = (const float*)d_in[7];
    const float* b2   = (const float*)d_in[8];
    const float* W3   = (const float*)d_in[9];
    const float* b3   = (const float*)d_in[10];
    float* out = (float*)d_out;

    unsigned short* AH = (unsigned short*)d_ws;
    float* fbase = (float*)((char*)d_ws + FLOAT_BYTE);
    const float4* nofuC = (const float4*)fbase;
    const float* W3T = fbase + 1024;
    float2* Pg = (float2*)((char*)d_ws + PSEG_BYTE);

    const int B = in_sizes[0] / NN;       // 262144
    const int blocks = B / 128;           // 2048
    const size_t main_lds = 2u * 128u * FROW * sizeof(unsigned short);   // 69632
    const size_t comb_lds = (4u * 4160u + 64u) * sizeof(float2);         // 133632

    hipLaunchKernelGGL(build_seg, dim3(20), dim3(64), 0, stream, mzi, Pg);
    hipLaunchKernelGGL(prep_weights, dim3(68), dim3(256), 0, stream,
                       W1, W2, W3, beta, det0, AH);
    hipLaunchKernelGGL(build_combine, dim3(LL), dim3(256), comb_lds, stream,
                       Pg, oph, AH);
    hipLaunchKernelGGL(ficonn_main, dim3(blocks), dim3(512), main_lds, stream,
                       x, b1, b2, b3, AH, nofuC, W3T, out);
}